// Round 13
// baseline (16.541 us; speedup 1.0000x reference)
//
#include <hip/hip_runtime.h>

// MosaicSDF: N=1024 points, G=512 grids, K=7 (343 nodes/grid).
// R13 = R12 skeleton with 512 thr (8 waves), 2 points/block, 16-lane
// groups (32 per block):
//   Phase 1: wave w sweeps 128 grids for point w>>2 (2 ballot rounds);
//     centers/scales pre-staged in LDS (alias of row buffer, one round of
//     512 float4); ballot-scan compacts (rx,ry,rz,gwr)+gid per wave seg.
//   Phase 2: 32 16-lane groups drain the pooled actives (CT=C0+C1).
//     Stage: scalar rbuf[22] (non-spilling pattern), software-pipelined
//     prefetch, commit to group's LDS row (pitch 344 dw; 4 groups/wave
//     tile the 32 banks 2x = free). Compute: lane owns (i,j)-rows
//     {sub,sub+16,sub+32} (7 nodes each, mul-shift div-7) + row-48 tail;
//     static dz2 register table; 4-step group reduce; route to acc0/acc1
//     by segment. No atomics, no workspace, one dispatch.

#define NPTS   1024
#define NGRIDS 512
#define TPB    512
#define NBLK   512             // 2 points per block
#define ROWF   344             // LDS row pitch in floats (343 + 1 pad)
#define STEP   (1.0f / 6.0f)
#define FSQRT(x) __builtin_amdgcn_sqrtf(x)

__global__ __launch_bounds__(TPB) void msdf_fused(
    const float* __restrict__ points,    // (N,3)
    const float* __restrict__ centers,   // (G,3)
    const float* __restrict__ scales,    // (G,)
    const float* __restrict__ vals,      // (G,343)
    float* __restrict__ out)             // (N,)
{
    __shared__ float  s_v[32][ROWF];          // 44,032 B rows (alias cen/scl)
    __shared__ float4 s_pair[8][128];         // 16,384 B (rx,ry,rz,gwr)
    __shared__ unsigned short s_gid[8][128];  // 2,048 B
    __shared__ int   s_c[8];
    __shared__ float s_d[8];
    __shared__ float s_red[8][2];

    const int bid  = blockIdx.x;
    const int t    = threadIdx.x;
    const int w    = t >> 6;             // wave 0..7
    const int lane = t & 63;
    const int grp  = t >> 4;             // 0..31: 16-lane group (pair slot)
    const int sub  = t & 15;

    // Stage centers (384 float4) + scales (128 float4) into alias of s_v.
    float* s_cen = &s_v[0][0];           // 1536 floats
    float* s_scl = s_cen + 1536;         // 512 floats
    {
        float4* dst = (float4*)s_cen;
        const float4* c4 = (const float4*)centers;
        const float4* s4 = (const float4*)scales;
        dst[t] = (t < 384) ? c4[t] : s4[t - 384];   // 512 float4, one round
    }

    const int   n  = (bid << 1) + (w >> 2);  // this wave's point
    const float px = points[n * 3 + 0];      // wave-uniform -> scalar loads
    const float py = points[n * 3 + 1];
    const float pz = points[n * 3 + 2];
    __syncthreads();

    // ---- Phase 1: activity sweep + ballot-scan compaction ----
    float dsum  = 0.0f;
    int   cbase = 0;
    #pragma unroll
    for (int r = 0; r < 2; ++r) {
        const int g = ((w & 3) << 7) + (r << 6) + lane;  // wave's 128 grids
        const float invs = 1.0f / s_scl[g];
        const float rx = (px - s_cen[g * 3 + 0]) * invs;
        const float ry = (py - s_cen[g * 3 + 1]) * invs;
        const float rz = (pz - s_cen[g * 3 + 2]) * invs;
        const float gwr = 1.0f - FSQRT(rx * rx + ry * ry + rz * rz);
        const bool  act = (gwr > 0.0f);
        const unsigned long long m = __ballot(act);
        if (act) {
            const int pos = cbase + (int)__popcll(m & ((1ull << lane) - 1ull));
            s_pair[w][pos] = make_float4(rx, ry, rz, gwr);
            s_gid[w][pos]  = (unsigned short)g;
            dsum += gwr;
        }
        cbase += (int)__popcll(m);
    }
    #pragma unroll
    for (int o = 32; o >= 1; o >>= 1) dsum += __shfl_xor(dsum, o);
    if (lane == 0) { s_c[w] = cbase; s_d[w] = dsum; }
    __syncthreads();                     // also closes s_cen/s_scl alias use

    const int o1 = s_c[0];
    const int o2 = o1 + s_c[1];
    const int o3 = o2 + s_c[2];
    const int o4 = o3 + s_c[3];
    const int o5 = o4 + s_c[4];
    const int o6 = o5 + s_c[5];
    const int o7 = o6 + s_c[6];
    const int CT = o7 + s_c[7];
    const float den0 = s_d[0] + s_d[1] + s_d[2] + s_d[3];
    const float den1 = s_d[4] + s_d[5] + s_d[6] + s_d[7];

    // ---- Phase 2: 32 16-lane groups drain the pooled pairs ----
    float acc0 = 0.0f, acc1 = 0.0f;
    if (CT > 0) {
        const int nch = (CT + 31) >> 5;
        float  rbuf[22];
        float4 pr;
        int    gid, seg;

        #define FETCH(a_) {                                               \
            const int pc = ((a_) < CT) ? (a_) : (CT - 1);                 \
            seg = (pc >= o1) + (pc >= o2) + (pc >= o3) + (pc >= o4)       \
                + (pc >= o5) + (pc >= o6) + (pc >= o7);                   \
            const int b0 = (seg == 0) ? 0 : (seg == 1) ? o1               \
                         : (seg == 2) ? o2 : (seg == 3) ? o3              \
                         : (seg == 4) ? o4 : (seg == 5) ? o5              \
                         : (seg == 6) ? o6 : o7;                          \
            pr  = s_pair[seg][pc - b0];                                   \
            gid = (int)s_gid[seg][pc - b0]; }

        #define LOADROW() {                                               \
            const float* __restrict__ grow = vals + gid * 343;            \
            _Pragma("unroll")                                             \
            for (int k = 0; k < 21; ++k) rbuf[k] = grow[sub + 16 * k];    \
            rbuf[21] = (sub < 7) ? grow[336 + sub] : 0.0f; }

        FETCH(grp); LOADROW();
        float* __restrict__ myv = &s_v[grp][0];

        for (int c = 0; c < nch; ++c) {
            // Commit staged row (chunk c) to this group's LDS row.
            #pragma unroll
            for (int k = 0; k < 21; ++k) myv[sub + 16 * k] = rbuf[k];
            if (sub < 7) myv[336 + sub] = rbuf[21];

            const float4 prc  = pr;
            const int    segc = seg;
            const float  gw   = (32 * c + grp < CT) ? prc.w : 0.0f;

            // Prefetch next chunk's pair+row while computing this one.
            if (c + 1 < nch) { FETCH(32 * (c + 1) + grp); LOADROW(); }

            float dz2[7];                            // static-indexed -> regs
            #pragma unroll
            for (int l = 0; l < 7; ++l) { const float d = prc.z - l * STEP; dz2[l] = d * d; }

            float ws = 0.0f, vs = 0.0f;
            #pragma unroll
            for (int rr = 0; rr < 3; ++rr) {
                const int rowid = sub + (rr << 4);           // 0..47
                const int i = (rowid * 9363) >> 16;          // rowid / 7
                const int j = rowid - i * 7;
                const float dxv = prc.x - (float)i * STEP;
                const float dyv = prc.y - (float)j * STEP;
                const float dxy = dxv * dxv + dyv * dyv;
                const float* __restrict__ vr = myv + rowid * 7;
                #pragma unroll
                for (int l = 0; l < 7; ++l) {
                    const float d2 = dxy + dz2[l];
                    const float wt = (d2 <= 1.0f) ? FSQRT(d2) : 0.0f;
                    ws += wt;
                    vs  = fmaf(wt, vr[l], vs);
                }
            }
            if (sub < 7) {                                   // row 48: (6,6,sub)
                const float dxv = prc.x - 1.0f;
                const float dyv = prc.y - 1.0f;
                const float dzv = prc.z - (float)sub * STEP;
                const float d2  = dxv * dxv + dyv * dyv + dzv * dzv;
                const float wt  = (d2 <= 1.0f) ? FSQRT(d2) : 0.0f;
                ws += wt;
                vs  = fmaf(wt, myv[336 + sub], vs);
            }
            #pragma unroll
            for (int o = 8; o >= 1; o >>= 1) {
                ws += __shfl_xor(ws, o);
                vs += __shfl_xor(vs, o);
            }
            const float interp = (ws > 0.0f) ? (vs / ws) : 0.0f;
            if (sub == 0) {
                const float contrib = interp * gw;
                if (segc < 4) acc0 += contrib;
                else          acc1 += contrib;
            }
        }
        #undef FETCH
        #undef LOADROW
    }

    // Block reduction: butterfly per wave, then cross-wave via LDS.
    #pragma unroll
    for (int o = 32; o >= 1; o >>= 1) {
        acc0 += __shfl_xor(acc0, o);
        acc1 += __shfl_xor(acc1, o);
    }
    if (lane == 0) { s_red[w][0] = acc0; s_red[w][1] = acc1; }
    __syncthreads();
    if (t < 2) {
        float nm = 0.0f;
        #pragma unroll
        for (int i = 0; i < 8; ++i) nm += s_red[i][t];
        const float dn = (t == 0) ? den0 : den1;
        out[(bid << 1) + t] = (dn > 0.0f) ? (nm / dn) : 0.0f;
    }
}

extern "C" void kernel_launch(void* const* d_in, const int* in_sizes, int n_in,
                              void* d_out, int out_size, void* d_ws, size_t ws_size,
                              hipStream_t stream) {
    const float* points  = (const float*)d_in[0];   // (1024,3)
    const float* centers = (const float*)d_in[1];   // (512,3)
    const float* scales  = (const float*)d_in[2];   // (512,)
    const float* vals    = (const float*)d_in[3];   // (512,7,7,7)
    float* out = (float*)d_out;                     // (1024,)

    msdf_fused<<<NBLK, TPB, 0, stream>>>(points, centers, scales, vals, out);
}